// Round 3
// baseline (1669.484 us; speedup 1.0000x reference)
//
#include <hip/hip_runtime.h>
#include <math.h>

#define NN 50000      // nodes
#define NE 800000     // edges
#define NP 200000     // link pairs
#define NF 128        // feature dim
#define NC 4          // feature chunks (32 feats = 64 B bf16 each; 3.2 MB/chunk fits per-XCD L2)
#define NEDGE_TOT (NE + NN)   // edges + self loops
#define NBLK 196              // ceil(NN/256)

typedef __attribute__((ext_vector_type(8))) short short8;
typedef __attribute__((ext_vector_type(4))) float float4v;

// ---- bf16 helpers (manual, RNE) ----
__device__ __forceinline__ float bf_lo(unsigned u) { return __uint_as_float(u << 16); }
__device__ __forceinline__ float bf_hi(unsigned u) { return __uint_as_float(u & 0xffff0000u); }
__device__ __forceinline__ unsigned short f2bf(float f) {
    unsigned u = __float_as_uint(f);
    return (unsigned short)((u + 0x7fffu + ((u >> 16) & 1u)) >> 16);
}
__device__ __forceinline__ unsigned pack2bf(float a, float b) {
    return (unsigned)f2bf(a) | ((unsigned)f2bf(b) << 16);
}

// ---------------------------------------------------------------------------
// CSR build
// ---------------------------------------------------------------------------
__global__ __launch_bounds__(256) void init_cnt_k(int* __restrict__ cnt) {
    int i = blockIdx.x * 256 + threadIdx.x;
    if (i < NN) cnt[i] = 1;  // self-loop
}

__global__ __launch_bounds__(256) void count_k(const int* __restrict__ ei,
                                               int* __restrict__ cnt) {
    int e = blockIdx.x * 256 + threadIdx.x;
    if (e < NE) atomicAdd(&cnt[ei[NE + e]], 1);
}

__global__ __launch_bounds__(256) void dinv_k(const int* __restrict__ cnt,
                                              float* __restrict__ dinv) {
    int i = blockIdx.x * 256 + threadIdx.x;
    if (i < NN) dinv[i] = rsqrtf((float)cnt[i]);
}

__global__ __launch_bounds__(256) void scan_reduce_k(const int* __restrict__ cnt,
                                                     int* __restrict__ bsum) {
    __shared__ int s[256];
    int t = threadIdx.x;
    int idx = blockIdx.x * 256 + t;
    s[t] = (idx < NN) ? cnt[idx] : 0;
    __syncthreads();
    for (int off = 128; off > 0; off >>= 1) {
        if (t < off) s[t] += s[t + off];
        __syncthreads();
    }
    if (t == 0) bsum[blockIdx.x] = s[0];
}

__global__ __launch_bounds__(256) void scan_bsums_k(const int* __restrict__ bsum,
                                                    int* __restrict__ boff) {
    __shared__ int s[256];
    int t = threadIdx.x;
    int v = (t < NBLK) ? bsum[t] : 0;
    s[t] = v;
    __syncthreads();
    for (int off = 1; off < 256; off <<= 1) {
        int add = (t >= off) ? s[t - off] : 0;
        __syncthreads();
        s[t] += add;
        __syncthreads();
    }
    if (t < NBLK) boff[t] = s[t] - v;
}

__global__ __launch_bounds__(256) void scan_down_k(const int* __restrict__ cnt,
                                                   const int* __restrict__ boff,
                                                   int* __restrict__ row_ptr,
                                                   int* __restrict__ wptr) {
    __shared__ int s[256];
    int t = threadIdx.x;
    int idx = blockIdx.x * 256 + t;
    int v = (idx < NN) ? cnt[idx] : 0;
    s[t] = v;
    __syncthreads();
    for (int off = 1; off < 256; off <<= 1) {
        int add = (t >= off) ? s[t - off] : 0;
        __syncthreads();
        s[t] += add;
        __syncthreads();
    }
    int excl = s[t] - v + boff[blockIdx.x];
    if (idx < NN) {
        row_ptr[idx] = excl;
        wptr[idx] = excl;
        if (idx == NN - 1) row_ptr[NN] = excl + v;
    }
}

__global__ __launch_bounds__(256) void scatter_k(const int* __restrict__ ei,
                                                 const float* __restrict__ dinv,
                                                 int* __restrict__ wptr,
                                                 int* __restrict__ cols,
                                                 float* __restrict__ norms) {
    int e = blockIdx.x * 256 + threadIdx.x;
    if (e >= NEDGE_TOT) return;
    int s, d;
    if (e < NE) { s = ei[e]; d = ei[NE + e]; }
    else        { s = d = e - NE; }
    int pos = atomicAdd(&wptr[d], 1);
    cols[pos]  = s;
    norms[pos] = dinv[s] * dinv[d];
}

// ---------------------------------------------------------------------------
// Casts: x fp32 [N][128] -> chunk-major bf16 [4][N][32]; W fp32 -> bf16 row-major
// ---------------------------------------------------------------------------
__global__ __launch_bounds__(256) void cast_x_k(const float* __restrict__ x,
                                                unsigned short* __restrict__ Xc) {
    int t = blockIdx.x * 256 + threadIdx.x;
    if (t >= NN * 16) return;
    int n = t >> 4, d = (t & 15) * 8;
    const float* p = x + (size_t)n * NF + d;
    float4 f0 = *(const float4*)p;
    float4 f1 = *(const float4*)(p + 4);
    uint4 q;
    q.x = pack2bf(f0.x, f0.y);
    q.y = pack2bf(f0.z, f0.w);
    q.z = pack2bf(f1.x, f1.y);
    q.w = pack2bf(f1.z, f1.w);
    *(uint4*)(Xc + (size_t)(d >> 5) * NN * 32 + (size_t)n * 32 + (d & 31)) = q;
}

__global__ __launch_bounds__(256) void cast_w_k(const float* __restrict__ W,
                                                unsigned short* __restrict__ Wb) {
    int t = blockIdx.x * 256 + threadIdx.x;
    if (t >= 128 * 128 / 8) return;
    int i = t * 8;
    float4 f0 = *(const float4*)(W + i);
    float4 f1 = *(const float4*)(W + i + 4);
    uint4 q;
    q.x = pack2bf(f0.x, f0.y);
    q.y = pack2bf(f0.z, f0.w);
    q.z = pack2bf(f1.x, f1.y);
    q.w = pack2bf(f1.z, f1.w);
    *(uint4*)(Wb + i) = q;
}

// ---------------------------------------------------------------------------
// MFMA GEMM: Y[n,f] = sum_d X[n,d]*W[f,d] + bias[f]
// X chunk-major bf16 [4][N][32]; W row-major bf16 [128][128]; Y chunk-major bf16.
// One wave: 16 rows x 128 cols (8 f-tiles), 4 k-steps of 32.
// A frag: A[m=lane&15][k=quad*8+j]; B frag: B'[n=lane&15][k=quad*8+j] (W rows);
// C/D: col=lane&15, row=quad*4+reg  (verified layouts, learn_hip m89/m120).
// ---------------------------------------------------------------------------
__global__ __launch_bounds__(256) void gemm_mfma_k(const unsigned short* __restrict__ Xc,
                                                   const unsigned short* __restrict__ Wb,
                                                   const float* __restrict__ bias,
                                                   unsigned short* __restrict__ Yc,
                                                   int nrows) {
    int wave = threadIdx.x >> 6, lane = threadIdx.x & 63;
    int rbase = blockIdx.x * 64 + wave * 16;
    if (rbase >= nrows) return;
    int quad = lane >> 4, mn = lane & 15;
    float4v acc[8];
#pragma unroll
    for (int ft = 0; ft < 8; ++ft) acc[ft] = (float4v){0.f, 0.f, 0.f, 0.f};
#pragma unroll
    for (int kb = 0; kb < 128; kb += 32) {
        int chunk = kb >> 5;
        short8 a = *(const short8*)(Xc + (size_t)chunk * NN * 32 +
                                    (size_t)(rbase + mn) * 32 + quad * 8);
#pragma unroll
        for (int ft = 0; ft < 8; ++ft) {
            short8 b = *(const short8*)(Wb + (size_t)(ft * 16 + mn) * 128 + kb + quad * 8);
            acc[ft] = __builtin_amdgcn_mfma_f32_16x16x32_bf16(a, b, acc[ft], 0, 0, 0);
        }
    }
#pragma unroll
    for (int ft = 0; ft < 8; ++ft) {
        int f = ft * 16 + mn;
        float bv = bias[f];
        size_t base = (size_t)(f >> 5) * NN * 32 + (f & 31);
#pragma unroll
        for (int r = 0; r < 4; ++r) {
            int row = rbase + quad * 4 + r;
            Yc[base + (size_t)row * 32] = f2bf(acc[ft][r] + bv);
        }
    }
}

// ---------------------------------------------------------------------------
// Chunked APPNP step: out[v] = 0.9 * sum_e norm_e * h[col_e] + 0.1 * x0[v]
// h/x0 chunk-major [4][N][32]. Grid (N/4, 4): blockIdx.y = chunk => chunk-major
// dispatch time windows keep the active 3.2 MB chunk L2-resident per XCD.
// One wave per (node, chunk): 8 groups x 8 lanes; each group gathers one edge's
// 64 B chunk-row (uint2/lane). Cross-group butterfly reduce. fp32 accumulate.
// rm_out: final layer-2 step writes row-major [N][128] for pair_k.
// ---------------------------------------------------------------------------
__global__ __launch_bounds__(256) void appnp_c_k(const unsigned short* __restrict__ h,
                                                 const unsigned short* __restrict__ x0,
                                                 unsigned short* __restrict__ out,
                                                 const int* __restrict__ row_ptr,
                                                 const int* __restrict__ cols,
                                                 const float* __restrict__ norms,
                                                 int relu, int rm_out) {
    int node = blockIdx.x * 4 + (threadIdx.x >> 6);
    int lane = threadIdx.x & 63;
    int c = blockIdx.y;
    int g = lane >> 3, li = lane & 7;
    const unsigned short* hc = h + (size_t)c * NN * 32;
    int beg = row_ptr[node], end = row_ptr[node + 1];
    float a0 = 0.f, a1 = 0.f, a2 = 0.f, a3 = 0.f;
    for (int e = beg; e < end; e += 64) {
        int m = end - e;
        if (m > 64) m = 64;
        int cr = 0;
        float w = 0.f;
        if (lane < m) { cr = cols[e + lane]; w = norms[e + lane]; }
        for (int j = 0; j < m; j += 8) {
            int src = j + g;                 // src >= m carries w=0, cr=0
            int cj = __shfl(cr, src, 64);
            float wj = __shfl(w, src, 64);
            uint2 q = *(const uint2*)(hc + (size_t)cj * 32 + li * 4);
            a0 += wj * bf_lo(q.x);
            a1 += wj * bf_hi(q.x);
            a2 += wj * bf_lo(q.y);
            a3 += wj * bf_hi(q.y);
        }
    }
#pragma unroll
    for (int off = 8; off < 64; off <<= 1) {
        a0 += __shfl_xor(a0, off, 64);
        a1 += __shfl_xor(a1, off, 64);
        a2 += __shfl_xor(a2, off, 64);
        a3 += __shfl_xor(a3, off, 64);
    }
    if (g == 0) {
        uint2 xq = *(const uint2*)(x0 + (size_t)c * NN * 32 + (size_t)node * 32 + li * 4);
        float r0 = 0.9f * a0 + 0.1f * bf_lo(xq.x);
        float r1 = 0.9f * a1 + 0.1f * bf_hi(xq.x);
        float r2 = 0.9f * a2 + 0.1f * bf_lo(xq.y);
        float r3 = 0.9f * a3 + 0.1f * bf_hi(xq.y);
        if (relu) {
            r0 = fmaxf(r0, 0.f); r1 = fmaxf(r1, 0.f);
            r2 = fmaxf(r2, 0.f); r3 = fmaxf(r3, 0.f);
        }
        uint2 oq;
        oq.x = pack2bf(r0, r1);
        oq.y = pack2bf(r2, r3);
        unsigned short* dst = rm_out ? (out + (size_t)node * NF + c * 32 + li * 4)
                                     : (out + (size_t)c * NN * 32 + (size_t)node * 32 + li * 4);
        *(uint2*)dst = oq;
    }
}

// ---------------------------------------------------------------------------
// Pair head (h row-major bf16): one wave per pair; lanes 0-31 = h[u], 32-63 = h[v].
// ---------------------------------------------------------------------------
__global__ __launch_bounds__(256) void pair_k(const unsigned short* __restrict__ h,
                                              const int* __restrict__ index,
                                              const float* __restrict__ W3,
                                              const float* __restrict__ b3,
                                              float* __restrict__ outp) {
    int gw = (blockIdx.x * 256 + threadIdx.x) >> 6;
    int lane = threadIdx.x & 63;
    if (gw >= NP) return;
    int half = lane >> 5, li = lane & 31;
    int u = index[gw * 2], v = index[gw * 2 + 1];
    int node = half ? v : u;
    uint2 q = *((const uint2*)(h + (size_t)node * NF) + li);
    float f0 = bf_lo(q.x), f1 = bf_hi(q.x), f2 = bf_lo(q.y), f3 = bf_hi(q.y);
    int fb = half * 128 + li * 4;
    float4 wa = *(const float4*)(W3 + fb);
    float4 wb = *(const float4*)(W3 + 256 + fb);
    float p0 = f0 * wa.x + f1 * wa.y + f2 * wa.z + f3 * wa.w;
    float p1 = f0 * wb.x + f1 * wb.y + f2 * wb.z + f3 * wb.w;
#pragma unroll
    for (int off = 32; off > 0; off >>= 1) {
        p0 += __shfl_xor(p0, off, 64);
        p1 += __shfl_xor(p1, off, 64);
    }
    if (lane == 0) {
        float s0 = p0 + b3[0], s1 = p1 + b3[1];
        float m = fmaxf(s0, s1);
        float lse = m + logf(expf(s0 - m) + expf(s1 - m));
        *(float2*)(outp + (size_t)gw * 2) = make_float2(s0 - lse, s1 - lse);
    }
}

// ---------------------------------------------------------------------------
// Launch
// ---------------------------------------------------------------------------
extern "C" void kernel_launch(void* const* d_in, const int* in_sizes, int n_in,
                              void* d_out, int out_size, void* d_ws, size_t ws_size,
                              hipStream_t stream) {
    const float* x  = (const float*)d_in[0];
    const int* ei   = (const int*)d_in[1];
    const int* idx  = (const int*)d_in[2];
    const float* W1 = (const float*)d_in[3];
    const float* b1 = (const float*)d_in[4];
    const float* W2 = (const float*)d_in[5];
    const float* b2 = (const float*)d_in[6];
    const float* W3 = (const float*)d_in[7];
    const float* b3 = (const float*)d_in[8];
    float* out = (float*)d_out;

    char* ws = (char*)d_ws;
    size_t off = 0;
    auto alloc = [&](size_t bytes) -> void* {
        void* p = ws + off;
        off = (off + bytes + 255) & ~(size_t)255;
        return p;
    };
    int*   cnt     = (int*)  alloc(NN * sizeof(int));
    float* dinv    = (float*)alloc(NN * sizeof(float));
    int*   row_ptr = (int*)  alloc((NN + 1) * sizeof(int));
    int*   wptr    = (int*)  alloc(NN * sizeof(int));
    int*   bsum    = (int*)  alloc(NBLK * sizeof(int));
    int*   boff    = (int*)  alloc(NBLK * sizeof(int));
    int*   cols    = (int*)  alloc(NEDGE_TOT * sizeof(int));
    float* norms   = (float*)alloc(NEDGE_TOT * sizeof(float));
    unsigned short* Xc  = (unsigned short*)alloc((size_t)NN * NF * 2);
    unsigned short* Wb1 = (unsigned short*)alloc(128 * 128 * 2);
    unsigned short* Wb2 = (unsigned short*)alloc(128 * 128 * 2);
    unsigned short* H0  = (unsigned short*)alloc((size_t)NN * NF * 2);
    unsigned short* HA  = (unsigned short*)alloc((size_t)NN * NF * 2);
    unsigned short* HB  = (unsigned short*)alloc((size_t)NN * NF * 2);

    const int gN    = (NN + 255) / 256;
    const int gE    = (NE + 255) / 256;
    const int gET   = (NEDGE_TOT + 255) / 256;
    const int gGemm = (NN + 63) / 64;            // 782 blocks, wave per 16 rows
    const dim3 gStep((NN + 3) / 4, NC);          // chunk-major windows
    const int gPair = (NP * 64 + 255) / 256;

    // ---- casts + gcn_norm + CSR ----
    cast_w_k<<<8, 256, 0, stream>>>(W1, Wb1);
    cast_w_k<<<8, 256, 0, stream>>>(W2, Wb2);
    cast_x_k<<<(NN * 16 + 255) / 256, 256, 0, stream>>>(x, Xc);
    init_cnt_k<<<gN, 256, 0, stream>>>(cnt);
    count_k<<<gE, 256, 0, stream>>>(ei, cnt);
    dinv_k<<<gN, 256, 0, stream>>>(cnt, dinv);
    scan_reduce_k<<<NBLK, 256, 0, stream>>>(cnt, bsum);
    scan_bsums_k<<<1, 256, 0, stream>>>(bsum, boff);
    scan_down_k<<<NBLK, 256, 0, stream>>>(cnt, boff, row_ptr, wptr);
    scatter_k<<<gET, 256, 0, stream>>>(ei, dinv, wptr, cols, norms);

    // ---- layer 1 ----
    gemm_mfma_k<<<gGemm, 256, 0, stream>>>(Xc, Wb1, b1, H0, NN);
    {
        const unsigned short* cur = H0;
        for (int k = 0; k < 10; ++k) {
            unsigned short* dst = (k & 1) ? HB : HA;
            appnp_c_k<<<gStep, 256, 0, stream>>>(cur, H0, dst, row_ptr, cols,
                                                 norms, (k == 9) ? 1 : 0, 0);
            cur = dst;
        }
    }
    // ---- layer 2 ----
    gemm_mfma_k<<<gGemm, 256, 0, stream>>>(HB, Wb2, b2, H0, NN);
    {
        const unsigned short* cur = H0;
        for (int k = 0; k < 10; ++k) {
            unsigned short* dst = (k & 1) ? HB : HA;
            appnp_c_k<<<gStep, 256, 0, stream>>>(cur, H0, dst, row_ptr, cols,
                                                 norms, (k == 9) ? 1 : 0,
                                                 (k == 9) ? 1 : 0);
            cur = dst;
        }
    }
    // ---- pair head ----
    pair_k<<<gPair, 256, 0, stream>>>(HB, idx, W3, b3, out);
}

// Round 4
// 919.322 us; speedup vs baseline: 1.8160x; 1.8160x over previous
//
#include <hip/hip_runtime.h>
#include <math.h>

#define NN 50000      // nodes
#define NE 800000     // edges
#define NP 200000     // link pairs
#define NF 128        // feature dim
#define NEDGE_TOT (NE + NN)   // edges + self loops
#define NBLK 196              // ceil(NN/256)

typedef __attribute__((ext_vector_type(8))) short short8;
typedef __attribute__((ext_vector_type(4))) float float4v;

// ---- bf16 helpers (manual, RNE) ----
__device__ __forceinline__ float bf_lo(unsigned u) { return __uint_as_float(u << 16); }
__device__ __forceinline__ float bf_hi(unsigned u) { return __uint_as_float(u & 0xffff0000u); }
__device__ __forceinline__ unsigned short f2bf(float f) {
    unsigned u = __float_as_uint(f);
    return (unsigned short)((u + 0x7fffu + ((u >> 16) & 1u)) >> 16);
}
__device__ __forceinline__ unsigned pack2bf(float a, float b) {
    return (unsigned)f2bf(a) | ((unsigned)f2bf(b) << 16);
}

// ---------------------------------------------------------------------------
// CSR build
// ---------------------------------------------------------------------------
__global__ __launch_bounds__(256) void init_cnt_k(int* __restrict__ cnt) {
    int i = blockIdx.x * 256 + threadIdx.x;
    if (i < NN) cnt[i] = 1;  // self-loop
}

__global__ __launch_bounds__(256) void count_k(const int* __restrict__ ei,
                                               int* __restrict__ cnt) {
    int e = blockIdx.x * 256 + threadIdx.x;
    if (e < NE) atomicAdd(&cnt[ei[NE + e]], 1);
}

// reduce + fused dinv
__global__ __launch_bounds__(256) void scan_reduce_k(const int* __restrict__ cnt,
                                                     int* __restrict__ bsum,
                                                     float* __restrict__ dinv) {
    __shared__ int s[256];
    int t = threadIdx.x;
    int idx = blockIdx.x * 256 + t;
    int v = (idx < NN) ? cnt[idx] : 0;
    if (idx < NN) dinv[idx] = rsqrtf((float)v);
    s[t] = v;
    __syncthreads();
    for (int off = 128; off > 0; off >>= 1) {
        if (t < off) s[t] += s[t + off];
        __syncthreads();
    }
    if (t == 0) bsum[blockIdx.x] = s[0];
}

__global__ __launch_bounds__(256) void scan_bsums_k(const int* __restrict__ bsum,
                                                    int* __restrict__ boff) {
    __shared__ int s[256];
    int t = threadIdx.x;
    int v = (t < NBLK) ? bsum[t] : 0;
    s[t] = v;
    __syncthreads();
    for (int off = 1; off < 256; off <<= 1) {
        int add = (t >= off) ? s[t - off] : 0;
        __syncthreads();
        s[t] += add;
        __syncthreads();
    }
    if (t < NBLK) boff[t] = s[t] - v;
}

__global__ __launch_bounds__(256) void scan_down_k(const int* __restrict__ cnt,
                                                   const int* __restrict__ boff,
                                                   int* __restrict__ row_ptr,
                                                   int* __restrict__ wptr) {
    __shared__ int s[256];
    int t = threadIdx.x;
    int idx = blockIdx.x * 256 + t;
    int v = (idx < NN) ? cnt[idx] : 0;
    s[t] = v;
    __syncthreads();
    for (int off = 1; off < 256; off <<= 1) {
        int add = (t >= off) ? s[t - off] : 0;
        __syncthreads();
        s[t] += add;
        __syncthreads();
    }
    int excl = s[t] - v + boff[blockIdx.x];
    if (idx < NN) {
        row_ptr[idx] = excl;
        wptr[idx] = excl;
        if (idx == NN - 1) row_ptr[NN] = excl + v;
    }
}

__global__ __launch_bounds__(256) void scatter_k(const int* __restrict__ ei,
                                                 const float* __restrict__ dinv,
                                                 int* __restrict__ wptr,
                                                 int* __restrict__ cols,
                                                 float* __restrict__ norms) {
    int e = blockIdx.x * 256 + threadIdx.x;
    if (e >= NEDGE_TOT) return;
    int s, d;
    if (e < NE) { s = ei[e]; d = ei[NE + e]; }
    else        { s = d = e - NE; }
    int pos = atomicAdd(&wptr[d], 1);
    cols[pos]  = s;
    norms[pos] = dinv[s] * dinv[d];
}

// ---------------------------------------------------------------------------
// Casts: x fp32 [N][128] -> row-major bf16; W fp32 -> bf16 row-major
// ---------------------------------------------------------------------------
__global__ __launch_bounds__(256) void cast_x_k(const float* __restrict__ x,
                                                unsigned short* __restrict__ Xb) {
    int t = blockIdx.x * 256 + threadIdx.x;
    if (t >= NN * 16) return;
    int i = t * 8;
    float4 f0 = *(const float4*)(x + i);
    float4 f1 = *(const float4*)(x + i + 4);
    uint4 q;
    q.x = pack2bf(f0.x, f0.y);
    q.y = pack2bf(f0.z, f0.w);
    q.z = pack2bf(f1.x, f1.y);
    q.w = pack2bf(f1.z, f1.w);
    *(uint4*)(Xb + i) = q;
}

__global__ __launch_bounds__(256) void cast_w_k(const float* __restrict__ W,
                                                unsigned short* __restrict__ Wb) {
    int t = blockIdx.x * 256 + threadIdx.x;
    if (t >= 128 * 128 / 8) return;
    int i = t * 8;
    float4 f0 = *(const float4*)(W + i);
    float4 f1 = *(const float4*)(W + i + 4);
    uint4 q;
    q.x = pack2bf(f0.x, f0.y);
    q.y = pack2bf(f0.z, f0.w);
    q.z = pack2bf(f1.x, f1.y);
    q.w = pack2bf(f1.z, f1.w);
    *(uint4*)(Wb + i) = q;
}

// ---------------------------------------------------------------------------
// MFMA GEMM: Y[n,f] = sum_d X[n,d]*W[f,d] + bias[f]; all row-major bf16.
// One wave: 16 rows x 128 cols (8 f-tiles), 4 k-steps of 32.
// A frag: A[m=lane&15][k=quad*8+j]; B frag: B'[n=lane&15][k=quad*8+j] (W rows);
// C/D: col=lane&15, row=quad*4+reg  (verified, learn_hip m89; passed rounds 2-3).
// Epilogue: LDS transpose (pad stride 136) -> vectorized uint4 row stores.
// ---------------------------------------------------------------------------
#define GPAD 136
__global__ __launch_bounds__(256) void gemm_mfma_k(const unsigned short* __restrict__ Xb,
                                                   const unsigned short* __restrict__ Wb,
                                                   const float* __restrict__ bias,
                                                   unsigned short* __restrict__ Yb,
                                                   int nrows) {
    __shared__ unsigned short sm[4 * 16 * GPAD];  // 17408 B
    int wave = threadIdx.x >> 6, lane = threadIdx.x & 63;
    int rbase = blockIdx.x * 64 + wave * 16;
    if (rbase >= nrows) return;
    int quad = lane >> 4, mn = lane & 15;
    float4v acc[8];
#pragma unroll
    for (int ft = 0; ft < 8; ++ft) acc[ft] = (float4v){0.f, 0.f, 0.f, 0.f};
#pragma unroll
    for (int kb = 0; kb < 128; kb += 32) {
        short8 a = *(const short8*)(Xb + (size_t)(rbase + mn) * NF + kb + quad * 8);
#pragma unroll
        for (int ft = 0; ft < 8; ++ft) {
            short8 b = *(const short8*)(Wb + (size_t)(ft * 16 + mn) * NF + kb + quad * 8);
            acc[ft] = __builtin_amdgcn_mfma_f32_16x16x32_bf16(a, b, acc[ft], 0, 0, 0);
        }
    }
    unsigned short* smw = sm + wave * 16 * GPAD;
#pragma unroll
    for (int ft = 0; ft < 8; ++ft) {
        float bv = bias[ft * 16 + mn];
#pragma unroll
        for (int r = 0; r < 4; ++r)
            smw[(quad * 4 + r) * GPAD + ft * 16 + mn] = f2bf(acc[ft][r] + bv);
    }
    __syncthreads();
#pragma unroll
    for (int t = 0; t < 4; ++t) {
        int rl = t * 4 + quad;
        uint4 q = *(const uint4*)(smw + rl * GPAD + mn * 8);
        *(uint4*)(Yb + (size_t)(rbase + rl) * NF + mn * 8) = q;
    }
}

// ---------------------------------------------------------------------------
// APPNP step, bf16 row-major h: out[v] = 0.9*sum_e norm_e*h[col_e] + 0.1*x0[v]
// One wave per dst node. 2 edges per gather instr (half-wave each, uint2/lane);
// x4-unrolled main loop + pairwise tail (no dummy gathers beyond m).
// Cross-half shfl_xor(32) merge; fp32 accumulation.
// ---------------------------------------------------------------------------
__global__ __launch_bounds__(256) void appnp_bf16_k(const unsigned short* __restrict__ h,
                                                    const unsigned short* __restrict__ x0,
                                                    unsigned short* __restrict__ out,
                                                    const int* __restrict__ row_ptr,
                                                    const int* __restrict__ cols,
                                                    const float* __restrict__ norms,
                                                    int relu) {
    int wid = (blockIdx.x * 256 + threadIdx.x) >> 6;
    int lane = threadIdx.x & 63;
    if (wid >= NN) return;
    int half = lane >> 5, li = lane & 31;
    int beg = row_ptr[wid], end = row_ptr[wid + 1];
    float a0 = 0.f, a1 = 0.f, a2 = 0.f, a3 = 0.f;
    for (int e = beg; e < end; e += 64) {
        int m = end - e;
        if (m > 64) m = 64;
        int c = 0;
        float w = 0.f;
        if (lane < m) { c = cols[e + lane]; w = norms[e + lane]; }
        int j = 0;
        for (; j + 8 <= m; j += 8) {
#pragma unroll
            for (int p = 0; p < 4; ++p) {
                int src = j + 2 * p + half;
                int cj = __shfl(c, src, 64);
                float wj = __shfl(w, src, 64);
                uint2 q = *((const uint2*)(h + (size_t)cj * NF) + li);
                a0 += wj * bf_lo(q.x);
                a1 += wj * bf_hi(q.x);
                a2 += wj * bf_lo(q.y);
                a3 += wj * bf_hi(q.y);
            }
        }
        for (; j < m; j += 2) {
            int src = j + half;               // src >= m carries w=0, c=0
            int cj = __shfl(c, src, 64);
            float wj = __shfl(w, src, 64);
            uint2 q = *((const uint2*)(h + (size_t)cj * NF) + li);
            a0 += wj * bf_lo(q.x);
            a1 += wj * bf_hi(q.x);
            a2 += wj * bf_lo(q.y);
            a3 += wj * bf_hi(q.y);
        }
    }
    a0 += __shfl_xor(a0, 32, 64);
    a1 += __shfl_xor(a1, 32, 64);
    a2 += __shfl_xor(a2, 32, 64);
    a3 += __shfl_xor(a3, 32, 64);
    if (half == 0) {
        uint2 xq = *((const uint2*)(x0 + (size_t)wid * NF) + li);
        float r0 = 0.9f * a0 + 0.1f * bf_lo(xq.x);
        float r1 = 0.9f * a1 + 0.1f * bf_hi(xq.x);
        float r2 = 0.9f * a2 + 0.1f * bf_lo(xq.y);
        float r3 = 0.9f * a3 + 0.1f * bf_hi(xq.y);
        if (relu) {
            r0 = fmaxf(r0, 0.f); r1 = fmaxf(r1, 0.f);
            r2 = fmaxf(r2, 0.f); r3 = fmaxf(r3, 0.f);
        }
        uint2 oq;
        oq.x = pack2bf(r0, r1);
        oq.y = pack2bf(r2, r3);
        *((uint2*)(out + (size_t)wid * NF) + li) = oq;
    }
}

// ---------------------------------------------------------------------------
// Pair head: one wave per pair; lanes 0-31 = h[u], 32-63 = h[v].
// ---------------------------------------------------------------------------
__global__ __launch_bounds__(256) void pair_k(const unsigned short* __restrict__ h,
                                              const int* __restrict__ index,
                                              const float* __restrict__ W3,
                                              const float* __restrict__ b3,
                                              float* __restrict__ outp) {
    int gw = (blockIdx.x * 256 + threadIdx.x) >> 6;
    int lane = threadIdx.x & 63;
    if (gw >= NP) return;
    int half = lane >> 5, li = lane & 31;
    int u = index[gw * 2], v = index[gw * 2 + 1];
    int node = half ? v : u;
    uint2 q = *((const uint2*)(h + (size_t)node * NF) + li);
    float f0 = bf_lo(q.x), f1 = bf_hi(q.x), f2 = bf_lo(q.y), f3 = bf_hi(q.y);
    int fb = half * 128 + li * 4;
    float4 wa = *(const float4*)(W3 + fb);
    float4 wb = *(const float4*)(W3 + 256 + fb);
    float p0 = f0 * wa.x + f1 * wa.y + f2 * wa.z + f3 * wa.w;
    float p1 = f0 * wb.x + f1 * wb.y + f2 * wb.z + f3 * wb.w;
#pragma unroll
    for (int off = 32; off > 0; off >>= 1) {
        p0 += __shfl_xor(p0, off, 64);
        p1 += __shfl_xor(p1, off, 64);
    }
    if (lane == 0) {
        float s0 = p0 + b3[0], s1 = p1 + b3[1];
        float m = fmaxf(s0, s1);
        float lse = m + logf(expf(s0 - m) + expf(s1 - m));
        *(float2*)(outp + (size_t)gw * 2) = make_float2(s0 - lse, s1 - lse);
    }
}

// ---------------------------------------------------------------------------
// Launch
// ---------------------------------------------------------------------------
extern "C" void kernel_launch(void* const* d_in, const int* in_sizes, int n_in,
                              void* d_out, int out_size, void* d_ws, size_t ws_size,
                              hipStream_t stream) {
    const float* x  = (const float*)d_in[0];
    const int* ei   = (const int*)d_in[1];
    const int* idx  = (const int*)d_in[2];
    const float* W1 = (const float*)d_in[3];
    const float* b1 = (const float*)d_in[4];
    const float* W2 = (const float*)d_in[5];
    const float* b2 = (const float*)d_in[6];
    const float* W3 = (const float*)d_in[7];
    const float* b3 = (const float*)d_in[8];
    float* out = (float*)d_out;

    char* ws = (char*)d_ws;
    size_t off = 0;
    auto alloc = [&](size_t bytes) -> void* {
        void* p = ws + off;
        off = (off + bytes + 255) & ~(size_t)255;
        return p;
    };
    int*   cnt     = (int*)  alloc(NN * sizeof(int));
    float* dinv    = (float*)alloc(NN * sizeof(float));
    int*   row_ptr = (int*)  alloc((NN + 1) * sizeof(int));
    int*   wptr    = (int*)  alloc(NN * sizeof(int));
    int*   bsum    = (int*)  alloc(NBLK * sizeof(int));
    int*   boff    = (int*)  alloc(NBLK * sizeof(int));
    int*   cols    = (int*)  alloc(NEDGE_TOT * sizeof(int));
    float* norms   = (float*)alloc(NEDGE_TOT * sizeof(float));
    unsigned short* Xb  = (unsigned short*)alloc((size_t)NN * NF * 2);
    unsigned short* Wb1 = (unsigned short*)alloc(128 * 128 * 2);
    unsigned short* Wb2 = (unsigned short*)alloc(128 * 128 * 2);
    unsigned short* H0  = (unsigned short*)alloc((size_t)NN * NF * 2);
    unsigned short* HA  = (unsigned short*)alloc((size_t)NN * NF * 2);
    unsigned short* HB  = (unsigned short*)alloc((size_t)NN * NF * 2);

    const int gN    = (NN + 255) / 256;
    const int gE    = (NE + 255) / 256;
    const int gET   = (NEDGE_TOT + 255) / 256;
    const int gGemm = (NN + 63) / 64;            // wave per 16 rows
    const int gStep = (NN * 64 + 255) / 256;     // wave per node
    const int gPair = (NP * 64 + 255) / 256;     // wave per pair

    // ---- casts + gcn_norm + CSR ----
    cast_w_k<<<8, 256, 0, stream>>>(W1, Wb1);
    cast_w_k<<<8, 256, 0, stream>>>(W2, Wb2);
    cast_x_k<<<(NN * 16 + 255) / 256, 256, 0, stream>>>(x, Xb);
    init_cnt_k<<<gN, 256, 0, stream>>>(cnt);
    count_k<<<gE, 256, 0, stream>>>(ei, cnt);
    scan_reduce_k<<<NBLK, 256, 0, stream>>>(cnt, bsum, dinv);
    scan_bsums_k<<<1, 256, 0, stream>>>(bsum, boff);
    scan_down_k<<<NBLK, 256, 0, stream>>>(cnt, boff, row_ptr, wptr);
    scatter_k<<<gET, 256, 0, stream>>>(ei, dinv, wptr, cols, norms);

    // ---- layer 1 ----
    gemm_mfma_k<<<gGemm, 256, 0, stream>>>(Xb, Wb1, b1, H0, NN);
    {
        const unsigned short* cur = H0;
        for (int k = 0; k < 10; ++k) {
            unsigned short* dst = (k & 1) ? HB : HA;
            appnp_bf16_k<<<gStep, 256, 0, stream>>>(cur, H0, dst, row_ptr, cols,
                                                    norms, (k == 9) ? 1 : 0);
            cur = dst;
        }
    }
    // ---- layer 2 ----
    gemm_mfma_k<<<gGemm, 256, 0, stream>>>(HB, Wb2, b2, H0, NN);
    {
        const unsigned short* cur = H0;
        for (int k = 0; k < 10; ++k) {
            unsigned short* dst = (k & 1) ? HB : HA;
            appnp_bf16_k<<<gStep, 256, 0, stream>>>(cur, H0, dst, row_ptr, cols,
                                                    norms, (k == 9) ? 1 : 0);
            cur = dst;
        }
    }
    // ---- pair head ----
    pair_k<<<gPair, 256, 0, stream>>>(HB, idx, W3, b3, out);
}

// Round 5
// 909.725 us; speedup vs baseline: 1.8352x; 1.0105x over previous
//
#include <hip/hip_runtime.h>
#include <math.h>

#define NN 50000      // nodes
#define NE 800000     // edges
#define NP 200000     // link pairs
#define NF 128        // feature dim
#define NEDGE_TOT (NE + NN)   // edges + self loops
#define NBLK 196              // ceil(NN/256)

typedef __attribute__((ext_vector_type(8))) short short8;
typedef __attribute__((ext_vector_type(4))) float float4v;

// ---- bf16 helpers (manual, RNE) ----
__device__ __forceinline__ float bf_lo(unsigned u) { return __uint_as_float(u << 16); }
__device__ __forceinline__ float bf_hi(unsigned u) { return __uint_as_float(u & 0xffff0000u); }
__device__ __forceinline__ unsigned short f2bf(float f) {
    unsigned u = __float_as_uint(f);
    return (unsigned short)((u + 0x7fffu + ((u >> 16) & 1u)) >> 16);
}
__device__ __forceinline__ unsigned pack2bf(float a, float b) {
    return (unsigned)f2bf(a) | ((unsigned)f2bf(b) << 16);
}

// ---------------------------------------------------------------------------
// CSR build
// ---------------------------------------------------------------------------
__global__ __launch_bounds__(256) void init_cnt_k(int* __restrict__ cnt) {
    int i = blockIdx.x * 256 + threadIdx.x;
    if (i < NN) cnt[i] = 1;  // self-loop
}

__global__ __launch_bounds__(256) void count_k(const int* __restrict__ ei,
                                               int* __restrict__ cnt) {
    int e = blockIdx.x * 256 + threadIdx.x;
    if (e < NE) atomicAdd(&cnt[ei[NE + e]], 1);
}

// reduce + fused dinv
__global__ __launch_bounds__(256) void scan_reduce_k(const int* __restrict__ cnt,
                                                     int* __restrict__ bsum,
                                                     float* __restrict__ dinv) {
    __shared__ int s[256];
    int t = threadIdx.x;
    int idx = blockIdx.x * 256 + t;
    int v = (idx < NN) ? cnt[idx] : 0;
    if (idx < NN) dinv[idx] = rsqrtf((float)v);
    s[t] = v;
    __syncthreads();
    for (int off = 128; off > 0; off >>= 1) {
        if (t < off) s[t] += s[t + off];
        __syncthreads();
    }
    if (t == 0) bsum[blockIdx.x] = s[0];
}

__global__ __launch_bounds__(256) void scan_bsums_k(const int* __restrict__ bsum,
                                                    int* __restrict__ boff) {
    __shared__ int s[256];
    int t = threadIdx.x;
    int v = (t < NBLK) ? bsum[t] : 0;
    s[t] = v;
    __syncthreads();
    for (int off = 1; off < 256; off <<= 1) {
        int add = (t >= off) ? s[t - off] : 0;
        __syncthreads();
        s[t] += add;
        __syncthreads();
    }
    if (t < NBLK) boff[t] = s[t] - v;
}

__global__ __launch_bounds__(256) void scan_down_k(const int* __restrict__ cnt,
                                                   const int* __restrict__ boff,
                                                   int* __restrict__ row_ptr,
                                                   int* __restrict__ wptr) {
    __shared__ int s[256];
    int t = threadIdx.x;
    int idx = blockIdx.x * 256 + t;
    int v = (idx < NN) ? cnt[idx] : 0;
    s[t] = v;
    __syncthreads();
    for (int off = 1; off < 256; off <<= 1) {
        int add = (t >= off) ? s[t - off] : 0;
        __syncthreads();
        s[t] += add;
        __syncthreads();
    }
    int excl = s[t] - v + boff[blockIdx.x];
    if (idx < NN) {
        row_ptr[idx] = excl;
        wptr[idx] = excl;
        if (idx == NN - 1) row_ptr[NN] = excl + v;
    }
}

// packed (col, norm) records: one 8 B store per edge instead of two 4 B stores
// (halves the line-dirty events driving the 85 MB WRITE_SIZE seen in round 4)
__global__ __launch_bounds__(256) void scatter_k(const int* __restrict__ ei,
                                                 const float* __restrict__ dinv,
                                                 int* __restrict__ wptr,
                                                 int2* __restrict__ rec) {
    int e = blockIdx.x * 256 + threadIdx.x;
    if (e >= NEDGE_TOT) return;
    int s, d;
    if (e < NE) { s = ei[e]; d = ei[NE + e]; }
    else        { s = d = e - NE; }
    int pos = atomicAdd(&wptr[d], 1);
    int2 r;
    r.x = s;
    r.y = __float_as_int(dinv[s] * dinv[d]);
    rec[pos] = r;
}

// ---------------------------------------------------------------------------
// Casts: x fp32 [N][128] -> row-major bf16; W fp32 -> bf16 row-major
// ---------------------------------------------------------------------------
__global__ __launch_bounds__(256) void cast_x_k(const float* __restrict__ x,
                                                unsigned short* __restrict__ Xb) {
    int t = blockIdx.x * 256 + threadIdx.x;
    if (t >= NN * 16) return;
    int i = t * 8;
    float4 f0 = *(const float4*)(x + i);
    float4 f1 = *(const float4*)(x + i + 4);
    uint4 q;
    q.x = pack2bf(f0.x, f0.y);
    q.y = pack2bf(f0.z, f0.w);
    q.z = pack2bf(f1.x, f1.y);
    q.w = pack2bf(f1.z, f1.w);
    *(uint4*)(Xb + i) = q;
}

__global__ __launch_bounds__(256) void cast_w_k(const float* __restrict__ W,
                                                unsigned short* __restrict__ Wb) {
    int t = blockIdx.x * 256 + threadIdx.x;
    if (t >= 128 * 128 / 8) return;
    int i = t * 8;
    float4 f0 = *(const float4*)(W + i);
    float4 f1 = *(const float4*)(W + i + 4);
    uint4 q;
    q.x = pack2bf(f0.x, f0.y);
    q.y = pack2bf(f0.z, f0.w);
    q.z = pack2bf(f1.x, f1.y);
    q.w = pack2bf(f1.z, f1.w);
    *(uint4*)(Wb + i) = q;
}

// ---------------------------------------------------------------------------
// MFMA GEMM: Y[n,f] = sum_d X[n,d]*W[f,d] + bias[f]; all row-major bf16.
// One wave: 16 rows x 128 cols (8 f-tiles), 4 k-steps of 32.
// A frag: A[m=lane&15][k=quad*8+j]; B frag: B'[n=lane&15][k=quad*8+j] (W rows);
// C/D: col=lane&15, row=quad*4+reg  (verified, learn_hip m89; passed rounds 2-4).
// Epilogue: LDS transpose (pad stride 136) -> vectorized uint4 row stores.
// ---------------------------------------------------------------------------
#define GPAD 136
__global__ __launch_bounds__(256) void gemm_mfma_k(const unsigned short* __restrict__ Xb,
                                                   const unsigned short* __restrict__ Wb,
                                                   const float* __restrict__ bias,
                                                   unsigned short* __restrict__ Yb,
                                                   int nrows) {
    __shared__ unsigned short sm[4 * 16 * GPAD];  // 17408 B
    int wave = threadIdx.x >> 6, lane = threadIdx.x & 63;
    int rbase = blockIdx.x * 64 + wave * 16;
    if (rbase >= nrows) return;
    int quad = lane >> 4, mn = lane & 15;
    float4v acc[8];
#pragma unroll
    for (int ft = 0; ft < 8; ++ft) acc[ft] = (float4v){0.f, 0.f, 0.f, 0.f};
#pragma unroll
    for (int kb = 0; kb < 128; kb += 32) {
        short8 a = *(const short8*)(Xb + (size_t)(rbase + mn) * NF + kb + quad * 8);
#pragma unroll
        for (int ft = 0; ft < 8; ++ft) {
            short8 b = *(const short8*)(Wb + (size_t)(ft * 16 + mn) * NF + kb + quad * 8);
            acc[ft] = __builtin_amdgcn_mfma_f32_16x16x32_bf16(a, b, acc[ft], 0, 0, 0);
        }
    }
    unsigned short* smw = sm + wave * 16 * GPAD;
#pragma unroll
    for (int ft = 0; ft < 8; ++ft) {
        float bv = bias[ft * 16 + mn];
#pragma unroll
        for (int r = 0; r < 4; ++r)
            smw[(quad * 4 + r) * GPAD + ft * 16 + mn] = f2bf(acc[ft][r] + bv);
    }
    __syncthreads();
#pragma unroll
    for (int t = 0; t < 4; ++t) {
        int rl = t * 4 + quad;
        uint4 q = *(const uint4*)(smw + rl * GPAD + mn * 8);
        *(uint4*)(Yb + (size_t)(rbase + rl) * NF + mn * 8) = q;
    }
}

// ---------------------------------------------------------------------------
// APPNP step, bf16 row-major h: out[v] = 0.9*sum_e norm_e*h[col_e] + 0.1*x0[v]
// One wave per dst node, 4 groups x 16 lanes; each group gathers one edge's
// full 256 B row (uint4/lane) -> 4 edges per gather instruction. Packed int2
// edge records. Predicated tail (no dummy gathers). fp32 accumulation.
// proj=1 (final layer-2 step): instead of writing h, fuse the pair-head
// projection puv[n] = (W3_0[:128].h, W3_1[:128].h, W3_0[128:].h, W3_1[128:].h).
// ---------------------------------------------------------------------------
__global__ __launch_bounds__(256) void appnp4_k(const unsigned short* __restrict__ h,
                                                const unsigned short* __restrict__ x0,
                                                unsigned short* __restrict__ out,
                                                const int* __restrict__ row_ptr,
                                                const int2* __restrict__ rec,
                                                int relu, int proj,
                                                const float* __restrict__ W3,
                                                float4* __restrict__ puv) {
    int wid = (blockIdx.x * 256 + threadIdx.x) >> 6;
    int lane = threadIdx.x & 63;
    if (wid >= NN) return;
    int g = lane >> 4, li = lane & 15;
    int beg = row_ptr[wid], end = row_ptr[wid + 1];
    float a0 = 0.f, a1 = 0.f, a2 = 0.f, a3 = 0.f;
    float a4 = 0.f, a5 = 0.f, a6 = 0.f, a7 = 0.f;
    for (int e = beg; e < end; e += 64) {
        int m = end - e;
        if (m > 64) m = 64;
        int c = 0;
        float w = 0.f;
        if (lane < m) { int2 q = rec[e + lane]; c = q.x; w = __int_as_float(q.y); }
        for (int j = 0; j < m; j += 4) {
            int src = j + g;
            int cj = __shfl(c, src, 64);
            float wj = __shfl(w, src, 64);
            if (src < m) {
                uint4 q = *((const uint4*)(h + (size_t)cj * NF) + li);
                a0 += wj * bf_lo(q.x);
                a1 += wj * bf_hi(q.x);
                a2 += wj * bf_lo(q.y);
                a3 += wj * bf_hi(q.y);
                a4 += wj * bf_lo(q.z);
                a5 += wj * bf_hi(q.z);
                a6 += wj * bf_lo(q.w);
                a7 += wj * bf_hi(q.w);
            }
        }
    }
#pragma unroll
    for (int off = 16; off < 64; off <<= 1) {
        a0 += __shfl_xor(a0, off, 64);
        a1 += __shfl_xor(a1, off, 64);
        a2 += __shfl_xor(a2, off, 64);
        a3 += __shfl_xor(a3, off, 64);
        a4 += __shfl_xor(a4, off, 64);
        a5 += __shfl_xor(a5, off, 64);
        a6 += __shfl_xor(a6, off, 64);
        a7 += __shfl_xor(a7, off, 64);
    }
    if (g == 0) {
        uint4 xq = *((const uint4*)(x0 + (size_t)wid * NF) + li);
        float r0 = 0.9f * a0 + 0.1f * bf_lo(xq.x);
        float r1 = 0.9f * a1 + 0.1f * bf_hi(xq.x);
        float r2 = 0.9f * a2 + 0.1f * bf_lo(xq.y);
        float r3 = 0.9f * a3 + 0.1f * bf_hi(xq.y);
        float r4 = 0.9f * a4 + 0.1f * bf_lo(xq.z);
        float r5 = 0.9f * a5 + 0.1f * bf_hi(xq.z);
        float r6 = 0.9f * a6 + 0.1f * bf_lo(xq.w);
        float r7 = 0.9f * a7 + 0.1f * bf_hi(xq.w);
        if (relu) {
            r0 = fmaxf(r0, 0.f); r1 = fmaxf(r1, 0.f);
            r2 = fmaxf(r2, 0.f); r3 = fmaxf(r3, 0.f);
            r4 = fmaxf(r4, 0.f); r5 = fmaxf(r5, 0.f);
            r6 = fmaxf(r6, 0.f); r7 = fmaxf(r7, 0.f);
        }
        if (!proj) {
            uint4 oq;
            oq.x = pack2bf(r0, r1);
            oq.y = pack2bf(r2, r3);
            oq.z = pack2bf(r4, r5);
            oq.w = pack2bf(r6, r7);
            *((uint4*)(out + (size_t)wid * NF) + li) = oq;
        } else {
            // lane li holds feats f = li*8 .. li*8+7
            int fb = li * 8;
            float4 wu0a = *(const float4*)(W3 + fb);
            float4 wu0b = *(const float4*)(W3 + fb + 4);
            float4 wv0a = *(const float4*)(W3 + 128 + fb);
            float4 wv0b = *(const float4*)(W3 + 128 + fb + 4);
            float4 wu1a = *(const float4*)(W3 + 256 + fb);
            float4 wu1b = *(const float4*)(W3 + 256 + fb + 4);
            float4 wv1a = *(const float4*)(W3 + 384 + fb);
            float4 wv1b = *(const float4*)(W3 + 384 + fb + 4);
            float du0 = r0 * wu0a.x + r1 * wu0a.y + r2 * wu0a.z + r3 * wu0a.w
                      + r4 * wu0b.x + r5 * wu0b.y + r6 * wu0b.z + r7 * wu0b.w;
            float du1 = r0 * wu1a.x + r1 * wu1a.y + r2 * wu1a.z + r3 * wu1a.w
                      + r4 * wu1b.x + r5 * wu1b.y + r6 * wu1b.z + r7 * wu1b.w;
            float dv0 = r0 * wv0a.x + r1 * wv0a.y + r2 * wv0a.z + r3 * wv0a.w
                      + r4 * wv0b.x + r5 * wv0b.y + r6 * wv0b.z + r7 * wv0b.w;
            float dv1 = r0 * wv1a.x + r1 * wv1a.y + r2 * wv1a.z + r3 * wv1a.w
                      + r4 * wv1b.x + r5 * wv1b.y + r6 * wv1b.z + r7 * wv1b.w;
#pragma unroll
            for (int off = 1; off < 16; off <<= 1) {
                du0 += __shfl_xor(du0, off, 64);
                du1 += __shfl_xor(du1, off, 64);
                dv0 += __shfl_xor(dv0, off, 64);
                dv1 += __shfl_xor(dv1, off, 64);
            }
            if (li == 0) puv[wid] = make_float4(du0, du1, dv0, dv1);
        }
    }
}

// ---------------------------------------------------------------------------
// Pair head from precomputed projections: one THREAD per pair, 32 B random
// reads from the 800 KB L2-resident puv table.
// ---------------------------------------------------------------------------
__global__ __launch_bounds__(256) void pair2_k(const float4* __restrict__ puv,
                                               const int2* __restrict__ index,
                                               const float* __restrict__ b3,
                                               float* __restrict__ outp) {
    int p = blockIdx.x * 256 + threadIdx.x;
    if (p >= NP) return;
    int2 uv = index[p];
    float4 a = puv[uv.x];
    float4 b = puv[uv.y];
    float s0 = a.x + b.z + b3[0];
    float s1 = a.y + b.w + b3[1];
    float m = fmaxf(s0, s1);
    float lse = m + logf(expf(s0 - m) + expf(s1 - m));
    *(float2*)(outp + (size_t)p * 2) = make_float2(s0 - lse, s1 - lse);
}

// ---------------------------------------------------------------------------
// Launch
// ---------------------------------------------------------------------------
extern "C" void kernel_launch(void* const* d_in, const int* in_sizes, int n_in,
                              void* d_out, int out_size, void* d_ws, size_t ws_size,
                              hipStream_t stream) {
    const float* x  = (const float*)d_in[0];
    const int* ei   = (const int*)d_in[1];
    const int* idx  = (const int*)d_in[2];
    const float* W1 = (const float*)d_in[3];
    const float* b1 = (const float*)d_in[4];
    const float* W2 = (const float*)d_in[5];
    const float* b2 = (const float*)d_in[6];
    const float* W3 = (const float*)d_in[7];
    const float* b3 = (const float*)d_in[8];
    float* out = (float*)d_out;

    char* ws = (char*)d_ws;
    size_t off = 0;
    auto alloc = [&](size_t bytes) -> void* {
        void* p = ws + off;
        off = (off + bytes + 255) & ~(size_t)255;
        return p;
    };
    int*   cnt     = (int*)  alloc(NN * sizeof(int));
    float* dinv    = (float*)alloc(NN * sizeof(float));
    int*   row_ptr = (int*)  alloc((NN + 1) * sizeof(int));
    int*   wptr    = (int*)  alloc(NN * sizeof(int));
    int*   bsum    = (int*)  alloc(NBLK * sizeof(int));
    int*   boff    = (int*)  alloc(NBLK * sizeof(int));
    int2*  rec     = (int2*) alloc((size_t)NEDGE_TOT * sizeof(int2));
    float4* puv    = (float4*)alloc((size_t)NN * sizeof(float4));
    unsigned short* Xb  = (unsigned short*)alloc((size_t)NN * NF * 2);
    unsigned short* Wb1 = (unsigned short*)alloc(128 * 128 * 2);
    unsigned short* Wb2 = (unsigned short*)alloc(128 * 128 * 2);
    unsigned short* H0  = (unsigned short*)alloc((size_t)NN * NF * 2);
    unsigned short* HA  = (unsigned short*)alloc((size_t)NN * NF * 2);
    unsigned short* HB  = (unsigned short*)alloc((size_t)NN * NF * 2);

    const int gN    = (NN + 255) / 256;
    const int gE    = (NE + 255) / 256;
    const int gET   = (NEDGE_TOT + 255) / 256;
    const int gGemm = (NN + 63) / 64;            // wave per 16 rows
    const int gStep = (NN * 64 + 255) / 256;     // wave per node
    const int gPair = (NP + 255) / 256;          // thread per pair

    // ---- casts + gcn_norm + CSR ----
    cast_w_k<<<8, 256, 0, stream>>>(W1, Wb1);
    cast_w_k<<<8, 256, 0, stream>>>(W2, Wb2);
    cast_x_k<<<(NN * 16 + 255) / 256, 256, 0, stream>>>(x, Xb);
    init_cnt_k<<<gN, 256, 0, stream>>>(cnt);
    count_k<<<gE, 256, 0, stream>>>(ei, cnt);
    scan_reduce_k<<<NBLK, 256, 0, stream>>>(cnt, bsum, dinv);
    scan_bsums_k<<<1, 256, 0, stream>>>(bsum, boff);
    scan_down_k<<<NBLK, 256, 0, stream>>>(cnt, boff, row_ptr, wptr);
    scatter_k<<<gET, 256, 0, stream>>>(ei, dinv, wptr, rec);

    // ---- layer 1 ----
    gemm_mfma_k<<<gGemm, 256, 0, stream>>>(Xb, Wb1, b1, H0, NN);
    {
        const unsigned short* cur = H0;
        for (int k = 0; k < 10; ++k) {
            unsigned short* dst = (k & 1) ? HB : HA;
            appnp4_k<<<gStep, 256, 0, stream>>>(cur, H0, dst, row_ptr, rec,
                                                (k == 9) ? 1 : 0, 0, W3, puv);
            cur = dst;
        }
    }
    // ---- layer 2 ----
    gemm_mfma_k<<<gGemm, 256, 0, stream>>>(HB, Wb2, b2, H0, NN);
    {
        const unsigned short* cur = H0;
        for (int k = 0; k < 10; ++k) {
            unsigned short* dst = (k & 1) ? HB : HA;
            appnp4_k<<<gStep, 256, 0, stream>>>(cur, H0, dst, row_ptr, rec,
                                                (k == 9) ? 1 : 0,
                                                (k == 9) ? 1 : 0, W3, puv);
            cur = dst;
        }
    }
    // ---- pair head ----
    pair2_k<<<gPair, 256, 0, stream>>>(puv, (const int2*)idx, b3, out);
}

// Round 6
// 841.564 us; speedup vs baseline: 1.9838x; 1.0810x over previous
//
#include <hip/hip_runtime.h>
#include <math.h>

#define NN 50000      // nodes
#define NE 800000     // edges
#define NP 200000     // link pairs
#define NF 128        // feature dim
#define NEDGE_TOT (NE + NN)   // edges + self loops
#define NBLK 196              // ceil(NN/256)

typedef __attribute__((ext_vector_type(8))) short short8;
typedef __attribute__((ext_vector_type(4))) float float4v;

// ---- bf16 helpers (manual, RNE) ----
__device__ __forceinline__ float bf_lo(unsigned u) { return __uint_as_float(u << 16); }
__device__ __forceinline__ float bf_hi(unsigned u) { return __uint_as_float(u & 0xffff0000u); }
__device__ __forceinline__ unsigned short f2bf(float f) {
    unsigned u = __float_as_uint(f);
    return (unsigned short)((u + 0x7fffu + ((u >> 16) & 1u)) >> 16);
}
__device__ __forceinline__ unsigned pack2bf(float a, float b) {
    return (unsigned)f2bf(a) | ((unsigned)f2bf(b) << 16);
}

// ---------------------------------------------------------------------------
// CSR build
// ---------------------------------------------------------------------------
__global__ __launch_bounds__(256) void init_cnt_k(int* __restrict__ cnt) {
    int i = blockIdx.x * 256 + threadIdx.x;
    if (i < NN) cnt[i] = 1;  // self-loop
}

__global__ __launch_bounds__(256) void count_k(const int* __restrict__ ei,
                                               int* __restrict__ cnt) {
    int e = blockIdx.x * 256 + threadIdx.x;
    if (e < NE) atomicAdd(&cnt[ei[NE + e]], 1);
}

// reduce + fused dinv
__global__ __launch_bounds__(256) void scan_reduce_k(const int* __restrict__ cnt,
                                                     int* __restrict__ bsum,
                                                     float* __restrict__ dinv) {
    __shared__ int s[256];
    int t = threadIdx.x;
    int idx = blockIdx.x * 256 + t;
    int v = (idx < NN) ? cnt[idx] : 0;
    if (idx < NN) dinv[idx] = rsqrtf((float)v);
    s[t] = v;
    __syncthreads();
    for (int off = 128; off > 0; off >>= 1) {
        if (t < off) s[t] += s[t + off];
        __syncthreads();
    }
    if (t == 0) bsum[blockIdx.x] = s[0];
}

__global__ __launch_bounds__(256) void scan_bsums_k(const int* __restrict__ bsum,
                                                    int* __restrict__ boff) {
    __shared__ int s[256];
    int t = threadIdx.x;
    int v = (t < NBLK) ? bsum[t] : 0;
    s[t] = v;
    __syncthreads();
    for (int off = 1; off < 256; off <<= 1) {
        int add = (t >= off) ? s[t - off] : 0;
        __syncthreads();
        s[t] += add;
        __syncthreads();
    }
    if (t < NBLK) boff[t] = s[t] - v;
}

__global__ __launch_bounds__(256) void scan_down_k(const int* __restrict__ cnt,
                                                   const int* __restrict__ boff,
                                                   int* __restrict__ row_ptr,
                                                   int* __restrict__ wptr) {
    __shared__ int s[256];
    int t = threadIdx.x;
    int idx = blockIdx.x * 256 + t;
    int v = (idx < NN) ? cnt[idx] : 0;
    s[t] = v;
    __syncthreads();
    for (int off = 1; off < 256; off <<= 1) {
        int add = (t >= off) ? s[t - off] : 0;
        __syncthreads();
        s[t] += add;
        __syncthreads();
    }
    int excl = s[t] - v + boff[blockIdx.x];
    if (idx < NN) {
        row_ptr[idx] = excl;
        wptr[idx] = excl;
        if (idx == NN - 1) row_ptr[NN] = excl + v;
    }
}

// packed (col, norm) records: one 8 B store per edge
__global__ __launch_bounds__(256) void scatter_k(const int* __restrict__ ei,
                                                 const float* __restrict__ dinv,
                                                 int* __restrict__ wptr,
                                                 int2* __restrict__ rec) {
    int e = blockIdx.x * 256 + threadIdx.x;
    if (e >= NEDGE_TOT) return;
    int s, d;
    if (e < NE) { s = ei[e]; d = ei[NE + e]; }
    else        { s = d = e - NE; }
    int pos = atomicAdd(&wptr[d], 1);
    int2 r;
    r.x = s;
    r.y = __float_as_int(dinv[s] * dinv[d]);
    rec[pos] = r;
}

// ---------------------------------------------------------------------------
// Casts
// ---------------------------------------------------------------------------
__global__ __launch_bounds__(256) void cast_x_k(const float* __restrict__ x,
                                                unsigned short* __restrict__ Xb) {
    int t = blockIdx.x * 256 + threadIdx.x;
    if (t >= NN * 16) return;
    int i = t * 8;
    float4 f0 = *(const float4*)(x + i);
    float4 f1 = *(const float4*)(x + i + 4);
    uint4 q;
    q.x = pack2bf(f0.x, f0.y);
    q.y = pack2bf(f0.z, f0.w);
    q.z = pack2bf(f1.x, f1.y);
    q.w = pack2bf(f1.z, f1.w);
    *(uint4*)(Xb + i) = q;
}

__global__ __launch_bounds__(256) void cast_w_k(const float* __restrict__ W,
                                                unsigned short* __restrict__ Wb) {
    int t = blockIdx.x * 256 + threadIdx.x;
    if (t >= 128 * 128 / 8) return;
    int i = t * 8;
    float4 f0 = *(const float4*)(W + i);
    float4 f1 = *(const float4*)(W + i + 4);
    uint4 q;
    q.x = pack2bf(f0.x, f0.y);
    q.y = pack2bf(f0.z, f0.w);
    q.z = pack2bf(f1.x, f1.y);
    q.w = pack2bf(f1.z, f1.w);
    *(uint4*)(Wb + i) = q;
}

// ---------------------------------------------------------------------------
// MFMA GEMM (verified layouts, rounds 2-5): Y = X @ W.T + b, row-major bf16.
// ---------------------------------------------------------------------------
#define GPAD 136
__global__ __launch_bounds__(256) void gemm_mfma_k(const unsigned short* __restrict__ Xb,
                                                   const unsigned short* __restrict__ Wb,
                                                   const float* __restrict__ bias,
                                                   unsigned short* __restrict__ Yb,
                                                   int nrows) {
    __shared__ unsigned short sm[4 * 16 * GPAD];  // 17408 B
    int wave = threadIdx.x >> 6, lane = threadIdx.x & 63;
    int rbase = blockIdx.x * 64 + wave * 16;
    if (rbase >= nrows) return;
    int quad = lane >> 4, mn = lane & 15;
    float4v acc[8];
#pragma unroll
    for (int ft = 0; ft < 8; ++ft) acc[ft] = (float4v){0.f, 0.f, 0.f, 0.f};
#pragma unroll
    for (int kb = 0; kb < 128; kb += 32) {
        short8 a = *(const short8*)(Xb + (size_t)(rbase + mn) * NF + kb + quad * 8);
#pragma unroll
        for (int ft = 0; ft < 8; ++ft) {
            short8 b = *(const short8*)(Wb + (size_t)(ft * 16 + mn) * NF + kb + quad * 8);
            acc[ft] = __builtin_amdgcn_mfma_f32_16x16x32_bf16(a, b, acc[ft], 0, 0, 0);
        }
    }
    unsigned short* smw = sm + wave * 16 * GPAD;
#pragma unroll
    for (int ft = 0; ft < 8; ++ft) {
        float bv = bias[ft * 16 + mn];
#pragma unroll
        for (int r = 0; r < 4; ++r)
            smw[(quad * 4 + r) * GPAD + ft * 16 + mn] = f2bf(acc[ft][r] + bv);
    }
    __syncthreads();
#pragma unroll
    for (int t = 0; t < 4; ++t) {
        int rl = t * 4 + quad;
        uint4 q = *(const uint4*)(smw + rl * GPAD + mn * 8);
        *(uint4*)(Yb + (size_t)(rbase + rl) * NF + mn * 8) = q;
    }
}

// ---------------------------------------------------------------------------
// APPNP step: ONE 16-LANE GROUP PER NODE (4 nodes/wave).
// Each group gathers its node's full 256 B rows (uint4/lane) -> one gather
// instruction per edge, ~deg independent loads in flight per group, x4 unroll.
// Lane li owns features li*8..li*8+7 across all edges => NO cross-lane
// reduction on the store path. fp32 accumulation.
// proj=1 (final layer-2 step): fuse pair-head projection
// puv[n] = (W3_0[:128].h, W3_1[:128].h, W3_0[128:].h, W3_1[128:].h)
// (needs only a 16-lane butterfly).
// ---------------------------------------------------------------------------
__global__ __launch_bounds__(256) void appnp_g_k(const unsigned short* __restrict__ h,
                                                 const unsigned short* __restrict__ x0,
                                                 unsigned short* __restrict__ out,
                                                 const int* __restrict__ row_ptr,
                                                 const int2* __restrict__ rec,
                                                 int relu, int proj,
                                                 const float* __restrict__ W3,
                                                 float4* __restrict__ puv) {
    int node = (blockIdx.x * 256 + threadIdx.x) >> 4;  // group id
    int li = threadIdx.x & 15;
    if (node >= NN) return;
    int gb = (threadIdx.x & 63) & ~15;  // group base lane within wave
    int beg = row_ptr[node], end = row_ptr[node + 1];
    float a0 = 0.f, a1 = 0.f, a2 = 0.f, a3 = 0.f;
    float a4 = 0.f, a5 = 0.f, a6 = 0.f, a7 = 0.f;
    for (int e = beg; e < end; e += 16) {
        int m = end - e;
        if (m > 16) m = 16;
        int c = 0;
        float w = 0.f;
        if (li < m) { int2 q = rec[e + li]; c = q.x; w = __int_as_float(q.y); }
        int j = 0;
        for (; j + 4 <= m; j += 4) {
            int c0 = __shfl(c, gb + j, 64),     c1 = __shfl(c, gb + j + 1, 64);
            int c2 = __shfl(c, gb + j + 2, 64), c3 = __shfl(c, gb + j + 3, 64);
            float w0 = __shfl(w, gb + j, 64),     w1 = __shfl(w, gb + j + 1, 64);
            float w2 = __shfl(w, gb + j + 2, 64), w3 = __shfl(w, gb + j + 3, 64);
            uint4 q0 = *((const uint4*)(h + (size_t)c0 * NF) + li);
            uint4 q1 = *((const uint4*)(h + (size_t)c1 * NF) + li);
            uint4 q2 = *((const uint4*)(h + (size_t)c2 * NF) + li);
            uint4 q3 = *((const uint4*)(h + (size_t)c3 * NF) + li);
            a0 += w0 * bf_lo(q0.x); a1 += w0 * bf_hi(q0.x);
            a2 += w0 * bf_lo(q0.y); a3 += w0 * bf_hi(q0.y);
            a4 += w0 * bf_lo(q0.z); a5 += w0 * bf_hi(q0.z);
            a6 += w0 * bf_lo(q0.w); a7 += w0 * bf_hi(q0.w);
            a0 += w1 * bf_lo(q1.x); a1 += w1 * bf_hi(q1.x);
            a2 += w1 * bf_lo(q1.y); a3 += w1 * bf_hi(q1.y);
            a4 += w1 * bf_lo(q1.z); a5 += w1 * bf_hi(q1.z);
            a6 += w1 * bf_lo(q1.w); a7 += w1 * bf_hi(q1.w);
            a0 += w2 * bf_lo(q2.x); a1 += w2 * bf_hi(q2.x);
            a2 += w2 * bf_lo(q2.y); a3 += w2 * bf_hi(q2.y);
            a4 += w2 * bf_lo(q2.z); a5 += w2 * bf_hi(q2.z);
            a6 += w2 * bf_lo(q2.w); a7 += w2 * bf_hi(q2.w);
            a0 += w3 * bf_lo(q3.x); a1 += w3 * bf_hi(q3.x);
            a2 += w3 * bf_lo(q3.y); a3 += w3 * bf_hi(q3.y);
            a4 += w3 * bf_lo(q3.z); a5 += w3 * bf_hi(q3.z);
            a6 += w3 * bf_lo(q3.w); a7 += w3 * bf_hi(q3.w);
        }
        for (; j < m; ++j) {
            int cj = __shfl(c, gb + j, 64);
            float wj = __shfl(w, gb + j, 64);
            uint4 q = *((const uint4*)(h + (size_t)cj * NF) + li);
            a0 += wj * bf_lo(q.x); a1 += wj * bf_hi(q.x);
            a2 += wj * bf_lo(q.y); a3 += wj * bf_hi(q.y);
            a4 += wj * bf_lo(q.z); a5 += wj * bf_hi(q.z);
            a6 += wj * bf_lo(q.w); a7 += wj * bf_hi(q.w);
        }
    }
    uint4 xq = *((const uint4*)(x0 + (size_t)node * NF) + li);
    float r0 = 0.9f * a0 + 0.1f * bf_lo(xq.x);
    float r1 = 0.9f * a1 + 0.1f * bf_hi(xq.x);
    float r2 = 0.9f * a2 + 0.1f * bf_lo(xq.y);
    float r3 = 0.9f * a3 + 0.1f * bf_hi(xq.y);
    float r4 = 0.9f * a4 + 0.1f * bf_lo(xq.z);
    float r5 = 0.9f * a5 + 0.1f * bf_hi(xq.z);
    float r6 = 0.9f * a6 + 0.1f * bf_lo(xq.w);
    float r7 = 0.9f * a7 + 0.1f * bf_hi(xq.w);
    if (relu) {
        r0 = fmaxf(r0, 0.f); r1 = fmaxf(r1, 0.f);
        r2 = fmaxf(r2, 0.f); r3 = fmaxf(r3, 0.f);
        r4 = fmaxf(r4, 0.f); r5 = fmaxf(r5, 0.f);
        r6 = fmaxf(r6, 0.f); r7 = fmaxf(r7, 0.f);
    }
    if (!proj) {
        uint4 oq;
        oq.x = pack2bf(r0, r1);
        oq.y = pack2bf(r2, r3);
        oq.z = pack2bf(r4, r5);
        oq.w = pack2bf(r6, r7);
        *((uint4*)(out + (size_t)node * NF) + li) = oq;
    } else {
        int fb = li * 8;
        float4 wu0a = *(const float4*)(W3 + fb);
        float4 wu0b = *(const float4*)(W3 + fb + 4);
        float4 wv0a = *(const float4*)(W3 + 128 + fb);
        float4 wv0b = *(const float4*)(W3 + 128 + fb + 4);
        float4 wu1a = *(const float4*)(W3 + 256 + fb);
        float4 wu1b = *(const float4*)(W3 + 256 + fb + 4);
        float4 wv1a = *(const float4*)(W3 + 384 + fb);
        float4 wv1b = *(const float4*)(W3 + 384 + fb + 4);
        float du0 = r0 * wu0a.x + r1 * wu0a.y + r2 * wu0a.z + r3 * wu0a.w
                  + r4 * wu0b.x + r5 * wu0b.y + r6 * wu0b.z + r7 * wu0b.w;
        float du1 = r0 * wu1a.x + r1 * wu1a.y + r2 * wu1a.z + r3 * wu1a.w
                  + r4 * wu1b.x + r5 * wu1b.y + r6 * wu1b.z + r7 * wu1b.w;
        float dv0 = r0 * wv0a.x + r1 * wv0a.y + r2 * wv0a.z + r3 * wv0a.w
                  + r4 * wv0b.x + r5 * wv0b.y + r6 * wv0b.z + r7 * wv0b.w;
        float dv1 = r0 * wv1a.x + r1 * wv1a.y + r2 * wv1a.z + r3 * wv1a.w
                  + r4 * wv1b.x + r5 * wv1b.y + r6 * wv1b.z + r7 * wv1b.w;
#pragma unroll
        for (int off = 1; off < 16; off <<= 1) {
            du0 += __shfl_xor(du0, off, 64);
            du1 += __shfl_xor(du1, off, 64);
            dv0 += __shfl_xor(dv0, off, 64);
            dv1 += __shfl_xor(dv1, off, 64);
        }
        if (li == 0) puv[node] = make_float4(du0, du1, dv0, dv1);
    }
}

// ---------------------------------------------------------------------------
// Pair head from precomputed projections: one thread per pair.
// ---------------------------------------------------------------------------
__global__ __launch_bounds__(256) void pair2_k(const float4* __restrict__ puv,
                                               const int2* __restrict__ index,
                                               const float* __restrict__ b3,
                                               float* __restrict__ outp) {
    int p = blockIdx.x * 256 + threadIdx.x;
    if (p >= NP) return;
    int2 uv = index[p];
    float4 a = puv[uv.x];
    float4 b = puv[uv.y];
    float s0 = a.x + b.z + b3[0];
    float s1 = a.y + b.w + b3[1];
    float m = fmaxf(s0, s1);
    float lse = m + logf(expf(s0 - m) + expf(s1 - m));
    *(float2*)(outp + (size_t)p * 2) = make_float2(s0 - lse, s1 - lse);
}

// ---------------------------------------------------------------------------
// Launch
// ---------------------------------------------------------------------------
extern "C" void kernel_launch(void* const* d_in, const int* in_sizes, int n_in,
                              void* d_out, int out_size, void* d_ws, size_t ws_size,
                              hipStream_t stream) {
    const float* x  = (const float*)d_in[0];
    const int* ei   = (const int*)d_in[1];
    const int* idx  = (const int*)d_in[2];
    const float* W1 = (const float*)d_in[3];
    const float* b1 = (const float*)d_in[4];
    const float* W2 = (const float*)d_in[5];
    const float* b2 = (const float*)d_in[6];
    const float* W3 = (const float*)d_in[7];
    const float* b3 = (const float*)d_in[8];
    float* out = (float*)d_out;

    char* ws = (char*)d_ws;
    size_t off = 0;
    auto alloc = [&](size_t bytes) -> void* {
        void* p = ws + off;
        off = (off + bytes + 255) & ~(size_t)255;
        return p;
    };
    int*   cnt     = (int*)  alloc(NN * sizeof(int));
    float* dinv    = (float*)alloc(NN * sizeof(float));
    int*   row_ptr = (int*)  alloc((NN + 1) * sizeof(int));
    int*   wptr    = (int*)  alloc(NN * sizeof(int));
    int*   bsum    = (int*)  alloc(NBLK * sizeof(int));
    int*   boff    = (int*)  alloc(NBLK * sizeof(int));
    int2*  rec     = (int2*) alloc((size_t)NEDGE_TOT * sizeof(int2));
    float4* puv    = (float4*)alloc((size_t)NN * sizeof(float4));
    unsigned short* Xb  = (unsigned short*)alloc((size_t)NN * NF * 2);
    unsigned short* Wb1 = (unsigned short*)alloc(128 * 128 * 2);
    unsigned short* Wb2 = (unsigned short*)alloc(128 * 128 * 2);
    unsigned short* H0  = (unsigned short*)alloc((size_t)NN * NF * 2);
    unsigned short* HA  = (unsigned short*)alloc((size_t)NN * NF * 2);
    unsigned short* HB  = (unsigned short*)alloc((size_t)NN * NF * 2);

    const int gN    = (NN + 255) / 256;
    const int gE    = (NE + 255) / 256;
    const int gET   = (NEDGE_TOT + 255) / 256;
    const int gGemm = (NN + 63) / 64;            // wave per 16 rows
    const int gStep = (NN * 16 + 255) / 256;     // 16-lane group per node
    const int gPair = (NP + 255) / 256;          // thread per pair

    // ---- casts + gcn_norm + CSR ----
    cast_w_k<<<8, 256, 0, stream>>>(W1, Wb1);
    cast_w_k<<<8, 256, 0, stream>>>(W2, Wb2);
    cast_x_k<<<(NN * 16 + 255) / 256, 256, 0, stream>>>(x, Xb);
    init_cnt_k<<<gN, 256, 0, stream>>>(cnt);
    count_k<<<gE, 256, 0, stream>>>(ei, cnt);
    scan_reduce_k<<<NBLK, 256, 0, stream>>>(cnt, bsum, dinv);
    scan_bsums_k<<<1, 256, 0, stream>>>(bsum, boff);
    scan_down_k<<<NBLK, 256, 0, stream>>>(cnt, boff, row_ptr, wptr);
    scatter_k<<<gET, 256, 0, stream>>>(ei, dinv, wptr, rec);

    // ---- layer 1 ----
    gemm_mfma_k<<<gGemm, 256, 0, stream>>>(Xb, Wb1, b1, H0, NN);
    {
        const unsigned short* cur = H0;
        for (int k = 0; k < 10; ++k) {
            unsigned short* dst = (k & 1) ? HB : HA;
            appnp_g_k<<<gStep, 256, 0, stream>>>(cur, H0, dst, row_ptr, rec,
                                                 (k == 9) ? 1 : 0, 0, W3, puv);
            cur = dst;
        }
    }
    // ---- layer 2 ----
    gemm_mfma_k<<<gGemm, 256, 0, stream>>>(HB, Wb2, b2, H0, NN);
    {
        const unsigned short* cur = H0;
        for (int k = 0; k < 10; ++k) {
            unsigned short* dst = (k & 1) ? HB : HA;
            appnp_g_k<<<gStep, 256, 0, stream>>>(cur, H0, dst, row_ptr, rec,
                                                 (k == 9) ? 1 : 0,
                                                 (k == 9) ? 1 : 0, W3, puv);
            cur = dst;
        }
    }
    // ---- pair head ----
    pair2_k<<<gPair, 256, 0, stream>>>(puv, (const int2*)idx, b3, out);
}